// Round 4
// baseline (15343.802 us; speedup 1.0000x reference)
//
#include <hip/hip_runtime.h>

// ConvGRU: 2-layer GRU, B=32, T=512, D=H=512, fp32 in/out, bf16 MFMA compute.
// Persistent wavefront pipeline, superstep s = layer0@t=s + layer1@t=s-1.
// Round-4: role-split waves (128 A-waves: u/r gates; 64 B-waves: o+update),
// weights register-resident (128 VGPR/wave), fully-unrolled K-chains,
// fuzzy barriers (arrive -> independent precompute -> spin), h*r pre-product.
// Cross-block state via relaxed agent-scope atomics (no fences in loop).

#define Bn 32
#define Tn 512
#define Dn 512
#define Hn 512
#define KKn 1024
#define NBLK 64
#define NTHR 192
#define NTHREADS (NBLK * NTHR)

typedef __bf16 bf16x8 __attribute__((ext_vector_type(8)));
typedef float floatx4 __attribute__((ext_vector_type(4)));

// ---- persistent device state ----
__device__ unsigned short g_h0b[2][Bn * Hn];   // layer0 h bf16 shadow (ping-pong)
__device__ unsigned short g_h1b[2][Bn * Hn];   // layer1 h bf16 shadow
__device__ unsigned short g_hr[2][Bn * Hn];    // h*r product bf16, per layer
__device__ float          g_u[2][Bn * Hn];     // u gate fp32, per layer
__device__ unsigned short g_xb[Bn * Tn * Dn];  // bf16 x
__device__ unsigned short g_Wrb[2 * Hn * KKn];
__device__ unsigned short g_Wub[2 * Hn * KKn];
__device__ unsigned short g_Wob[2 * Hn * KKn];
__device__ unsigned long long g_slot[NBLK * 8]; // per-block epoch slots

__device__ __forceinline__ bf16x8 ldb8(const unsigned short* p) {
    return *reinterpret_cast<const bf16x8*>(p);
}
__device__ __forceinline__ unsigned short f2b(float f) {
    union { float f; unsigned u; } v; v.f = f;
    unsigned u = v.u;
    return (unsigned short)((u + 0x7fffu + ((u >> 16) & 1u)) >> 16);  // RNE
}
__device__ __forceinline__ float b2f(unsigned b) {
    union { unsigned u; float f; } v; v.u = b << 16; return v.f;
}

// relaxed agent-scope atomics (device-coherent, no cache maintenance)
__device__ __forceinline__ unsigned long long ald8(const void* p) {
    return __hip_atomic_load((const unsigned long long*)p, __ATOMIC_RELAXED,
                             __HIP_MEMORY_SCOPE_AGENT);
}
__device__ __forceinline__ void ast8(void* p, unsigned long long v) {
    __hip_atomic_store((unsigned long long*)p, v, __ATOMIC_RELAXED,
                       __HIP_MEMORY_SCOPE_AGENT);
}
__device__ __forceinline__ unsigned ald4u(const unsigned* p) {
    return __hip_atomic_load(p, __ATOMIC_RELAXED, __HIP_MEMORY_SCOPE_AGENT);
}
__device__ __forceinline__ float ald4f(const float* p) {
    return __hip_atomic_load(p, __ATOMIC_RELAXED, __HIP_MEMORY_SCOPE_AGENT);
}
__device__ __forceinline__ void ast4f(float* p, float v) {
    __hip_atomic_store(p, v, __ATOMIC_RELAXED, __HIP_MEMORY_SCOPE_AGENT);
}
__device__ __forceinline__ void ast4u(unsigned* p, unsigned v) {
    __hip_atomic_store(p, v, __ATOMIC_RELAXED, __HIP_MEMORY_SCOPE_AGENT);
}
__device__ __forceinline__ bf16x8 ald_bf8(const unsigned short* p) {
    union { unsigned long long u; __bf16 b[4]; } a, b;
    a.u = ald8(p);
    b.u = ald8(p + 4);
    bf16x8 r;
    r[0] = a.b[0]; r[1] = a.b[1]; r[2] = a.b[2]; r[3] = a.b[3];
    r[4] = b.b[0]; r[5] = b.b[1]; r[6] = b.b[2]; r[7] = b.b[3];
    return r;
}

// per-wave spin: 64 lanes scan the 64 block slots
__device__ __forceinline__ void spin(unsigned long long tgt, int lane) {
    while (true) {
        unsigned long long v = ald8(&g_slot[lane * 8]);
        if (__all(v >= tgt)) break;
        __builtin_amdgcn_s_sleep(1);
    }
}

__device__ __forceinline__ void cvt_arr(const float* __restrict__ src,
                                        unsigned short* __restrict__ dst,
                                        int n, int gtid) {
    for (int i = gtid * 4; i < n; i += NTHREADS * 4) {
        floatx4 v = *reinterpret_cast<const floatx4*>(src + i);
        ushort4 pack = make_ushort4(f2b(v[0]), f2b(v[1]), f2b(v[2]), f2b(v[3]));
        *reinterpret_cast<ushort4*>(dst + i) = pack;
    }
}

__device__ __forceinline__ floatx4 mfma(bf16x8 a, bf16x8 b, floatx4 c) {
    return __builtin_amdgcn_mfma_f32_16x16x32_bf16(a, b, c, 0, 0, 0);
}

__global__ __launch_bounds__(NTHR, 1) void gru_persist(
    const float* __restrict__ x,
    const float* __restrict__ Wr, const float* __restrict__ br,
    const float* __restrict__ Wu, const float* __restrict__ bu,
    const float* __restrict__ Wo, const float* __restrict__ bo,
    float* __restrict__ out)
{
    const int tid  = threadIdx.x;
    const int lane = tid & 63;
    const int widx = tid >> 6;
    const int quad = lane >> 4;
    const int lo   = lane & 15;
    const bool isA = (widx < 2);
    const int gwA  = blockIdx.x * 2 + widx;  // 0..127 (A-waves)
    const int gwB  = blockIdx.x;             // 0..63  (B-waves)

    unsigned long long ep =
        __hip_atomic_load(&g_slot[blockIdx.x * 8], __ATOMIC_RELAXED,
                          __HIP_MEMORY_SCOPE_AGENT);

    // ---- launch init: zero h shadows; fp32 -> bf16 conversions ----
    {
        int gtid = blockIdx.x * NTHR + tid;
        unsigned* h0 = (unsigned*)&g_h0b[0][0];
        unsigned* h1 = (unsigned*)&g_h1b[0][0];
        for (int i = gtid; i < Bn * Hn; i += NTHREADS) {
            ast4u(h0 + i, 0u);
            ast4u(h1 + i, 0u);
        }
        cvt_arr(x,  g_xb,  Bn * Tn * Dn, gtid);
        cvt_arr(Wr, g_Wrb, 2 * Hn * KKn, gtid);
        cvt_arr(Wu, g_Wub, 2 * Hn * KKn, gtid);
        cvt_arr(Wo, g_Wob, 2 * Hn * KKn, gtid);
        __threadfence();   // once per launch: push converted data past L2
    }
    ep++;
    __syncthreads();
    if (tid == 0) ast8(&g_slot[blockIdx.x * 8], ep);
    spin(ep, lane);

    // ---- role parameters + register-resident weights ----
    int lA = 0, gA = 0, n0A = 0, lB = 0, n0B = 0;
    float biasA = 0.f, biasB = 0.f;
    bf16x8 wreg[32];
    {
        const unsigned short* Wsrc;
        int nrow;
        if (isA) {
            lA = gwA >> 6; gA = (gwA >> 5) & 1; n0A = (gwA & 31) * 16;
            Wsrc = (gA ? g_Wrb : g_Wub) + (size_t)lA * Hn * KKn;
            nrow = n0A;
            biasA = (gA ? br : bu)[lA * Hn + n0A + lo];
        } else {
            lB = gwB >> 5; n0B = (gwB & 31) * 16;
            Wsrc = g_Wob + (size_t)lB * Hn * KKn;
            nrow = n0B;
            biasB = bo[lB * Hn + n0B + lo];
        }
        const unsigned short* wp = Wsrc + (size_t)(nrow + lo) * KKn + quad * 8;
        #pragma unroll
        for (int i = 0; i < 32; ++i) wreg[i] = ldb8(wp + i * 32);
    }

    // A layer0: precompute x-part for s=0
    floatx4 pacc0 = {0.f,0.f,0.f,0.f}, pacc1 = {0.f,0.f,0.f,0.f};
    if (isA && lA == 0) {
        const unsigned short* p0 = g_xb + (size_t)lo * (Tn * Dn) + quad * 8;
        const unsigned short* p1 = g_xb + (size_t)(16 + lo) * (Tn * Dn) + quad * 8;
        #pragma unroll
        for (int i = 0; i < 16; ++i) {
            pacc0 = mfma(ldb8(p0 + i * 32), wreg[i], pacc0);
            pacc1 = mfma(ldb8(p1 + i * 32), wreg[i], pacc1);
        }
    }
    float hreg0[4] = {0.f,0.f,0.f,0.f}, hreg1[4] = {0.f,0.f,0.f,0.f};
    floatx4 bacc0 = {0.f,0.f,0.f,0.f}, bacc1 = {0.f,0.f,0.f,0.f};

    for (int s = 0; s <= Tn; ++s) {
        const int cur = s & 1, nxt = cur ^ 1;

        // ===== Phase A compute (A-waves): u and h*r(sigmoid) =====
        if (isA) {
            bool actA = (lA == 0) ? (s < Tn) : (s >= 1);
            if (actA) {
                floatx4 a0, a1;
                const unsigned short* hs = (lA == 0) ? g_h0b[cur] : g_h1b[cur];
                if (lA == 0) { a0 = pacc0; a1 = pacc1; }
                else {
                    a0 = floatx4{0.f,0.f,0.f,0.f}; a1 = a0;
                    const unsigned short* p0 = g_h0b[cur] + (size_t)lo * Hn + quad * 8;
                    const unsigned short* p1 = g_h0b[cur] + (size_t)(16 + lo) * Hn + quad * 8;
                    #pragma unroll
                    for (int i = 0; i < 16; ++i) {
                        a0 = mfma(ald_bf8(p0 + i * 32), wreg[i], a0);
                        a1 = mfma(ald_bf8(p1 + i * 32), wreg[i], a1);
                    }
                }
                // r-waves: fetch own h-tile values early (overlaps chain below)
                float hh0[4] = {0,0,0,0}, hh1[4] = {0,0,0,0};
                if (gA == 1) {
                    #pragma unroll
                    for (int rr = 0; rr < 4; ++rr) {
                        int b0 = quad * 4 + rr;
                        unsigned w0 = ald4u((const unsigned*)(hs + (size_t)b0 * Hn + n0A + (lo & ~1)));
                        unsigned w1 = ald4u((const unsigned*)(hs + (size_t)(16 + b0) * Hn + n0A + (lo & ~1)));
                        hh0[rr] = b2f((lo & 1) ? (w0 >> 16) : (w0 & 0xffffu));
                        hh1[rr] = b2f((lo & 1) ? (w1 >> 16) : (w1 & 0xffffu));
                    }
                }
                // h-part
                {
                    const unsigned short* p0 = hs + (size_t)lo * Hn + quad * 8;
                    const unsigned short* p1 = hs + (size_t)(16 + lo) * Hn + quad * 8;
                    #pragma unroll
                    for (int i = 0; i < 16; ++i) {
                        a0 = mfma(ald_bf8(p0 + i * 32), wreg[16 + i], a0);
                        a1 = mfma(ald_bf8(p1 + i * 32), wreg[16 + i], a1);
                    }
                }
                if (gA == 0) {
                    float* up = g_u[lA];
                    #pragma unroll
                    for (int rr = 0; rr < 4; ++rr) {
                        int b0 = quad * 4 + rr;
                        ast4f(up + (size_t)b0 * Hn + n0A + lo,
                              1.f / (1.f + __expf(-(a0[rr] + biasA))));
                        ast4f(up + (size_t)(16 + b0) * Hn + n0A + lo,
                              1.f / (1.f + __expf(-(a1[rr] + biasA))));
                    }
                } else {
                    unsigned short* hrp = g_hr[lA];
                    #pragma unroll
                    for (int rr = 0; rr < 4; ++rr) {
                        int b0 = quad * 4 + rr;
                        float r0 = 1.f / (1.f + __expf(-(a0[rr] + biasA)));
                        float r1 = 1.f / (1.f + __expf(-(a1[rr] + biasA)));
                        unsigned w0 = f2b(hh0[rr] * r0), w1 = f2b(hh1[rr] * r1);
                        unsigned q0 = __shfl_xor((int)w0, 1);
                        unsigned q1 = __shfl_xor((int)w1, 1);
                        if ((lo & 1) == 0) {
                            ast4u((unsigned*)(hrp + (size_t)b0 * Hn + n0A + lo), w0 | (q0 << 16));
                            ast4u((unsigned*)(hrp + (size_t)(16 + b0) * Hn + n0A + lo), w1 | (q1 << 16));
                        }
                    }
                }
            }
        }

        // ===== alpha barrier: arrive =====
        ep++;
        __syncthreads();
        if (tid == 0) ast8(&g_slot[blockIdx.x * 8], ep);

        // ===== precompute window (overlaps alpha spin / B compute) =====
        if (!isA) {
            bool act = (lB == 0) ? (s < Tn) : (s >= 1);
            bacc0 = floatx4{0.f,0.f,0.f,0.f}; bacc1 = bacc0;
            if (act) {
                if (lB == 0) {
                    const unsigned short* p0 = g_xb + (size_t)s * Dn + (size_t)lo * (Tn * Dn) + quad * 8;
                    const unsigned short* p1 = g_xb + (size_t)s * Dn + (size_t)(16 + lo) * (Tn * Dn) + quad * 8;
                    #pragma unroll
                    for (int i = 0; i < 16; ++i) {
                        bacc0 = mfma(ldb8(p0 + i * 32), wreg[i], bacc0);
                        bacc1 = mfma(ldb8(p1 + i * 32), wreg[i], bacc1);
                    }
                } else {
                    const unsigned short* p0 = g_h0b[cur] + (size_t)lo * Hn + quad * 8;
                    const unsigned short* p1 = g_h0b[cur] + (size_t)(16 + lo) * Hn + quad * 8;
                    #pragma unroll
                    for (int i = 0; i < 16; ++i) {
                        bacc0 = mfma(ald_bf8(p0 + i * 32), wreg[i], bacc0);
                        bacc1 = mfma(ald_bf8(p1 + i * 32), wreg[i], bacc1);
                    }
                }
            }
        } else if (lA == 0 && s + 1 < Tn) {
            const unsigned short* p0 = g_xb + (size_t)(s + 1) * Dn + (size_t)lo * (Tn * Dn) + quad * 8;
            const unsigned short* p1 = g_xb + (size_t)(s + 1) * Dn + (size_t)(16 + lo) * (Tn * Dn) + quad * 8;
            pacc0 = floatx4{0.f,0.f,0.f,0.f}; pacc1 = pacc0;
            #pragma unroll
            for (int i = 0; i < 16; ++i) {
                pacc0 = mfma(ldb8(p0 + i * 32), wreg[i], pacc0);
                pacc1 = mfma(ldb8(p1 + i * 32), wreg[i], pacc1);
            }
        }

        // ===== B-waves: spin alpha, then (h*r)@Wo + update =====
        if (!isA) {
            spin(ep, lane);
            bool act = (lB == 0) ? (s < Tn) : (s >= 1);
            if (act) {
                const unsigned short* HR = g_hr[lB];
                const unsigned short* p0 = HR + (size_t)lo * Hn + quad * 8;
                const unsigned short* p1 = HR + (size_t)(16 + lo) * Hn + quad * 8;
                #pragma unroll
                for (int i = 0; i < 16; ++i) {
                    bacc0 = mfma(ald_bf8(p0 + i * 32), wreg[16 + i], bacc0);
                    bacc1 = mfma(ald_bf8(p1 + i * 32), wreg[16 + i], bacc1);
                }
                const float* up = g_u[lB];
                unsigned short* hbn = (lB == 0) ? g_h0b[nxt] : g_h1b[nxt];
                bool fin = (lB == 0) ? (s == Tn - 1) : (s == Tn);
                #pragma unroll
                for (int rr = 0; rr < 4; ++rr) {
                    int b0 = quad * 4 + rr;
                    size_t i0 = (size_t)b0 * Hn + n0B + lo;
                    size_t i1 = (size_t)(16 + b0) * Hn + n0B + lo;
                    float o0 = tanhf(bacc0[rr] + biasB);
                    float o1 = tanhf(bacc1[rr] + biasB);
                    float u0 = ald4f(up + i0);
                    float u1 = ald4f(up + i1);
                    hreg0[rr] += u0 * (o0 - hreg0[rr]);
                    hreg1[rr] += u1 * (o1 - hreg1[rr]);
                    unsigned w0 = f2b(hreg0[rr]), w1 = f2b(hreg1[rr]);
                    unsigned q0 = __shfl_xor((int)w0, 1);
                    unsigned q1 = __shfl_xor((int)w1, 1);
                    if ((lo & 1) == 0) {
                        ast4u((unsigned*)(hbn + i0), w0 | (q0 << 16));
                        ast4u((unsigned*)(hbn + i1), w1 | (q1 << 16));
                    }
                    if (fin) {
                        out[(size_t)lB * Bn * Hn + i0] = hreg0[rr];
                        out[(size_t)lB * Bn * Hn + i1] = hreg1[rr];
                    }
                }
            }
        }

        // ===== beta barrier =====
        ep++;
        __syncthreads();
        if (tid == 0) ast8(&g_slot[blockIdx.x * 8], ep);
        spin(ep, lane);
    }
}

extern "C" void kernel_launch(void* const* d_in, const int* in_sizes, int n_in,
                              void* d_out, int out_size, void* d_ws, size_t ws_size,
                              hipStream_t stream) {
    const float* x  = (const float*)d_in[0];
    const float* Wr = (const float*)d_in[1];
    const float* br = (const float*)d_in[2];
    const float* Wu = (const float*)d_in[3];
    const float* bu = (const float*)d_in[4];
    const float* Wo = (const float*)d_in[5];
    const float* bo = (const float*)d_in[6];
    float* out = (float*)d_out;

    gru_persist<<<NBLK, NTHR, 0, stream>>>(x, Wr, br, Wu, bu, Wo, bo, out);
}

// Round 5
// 9467.879 us; speedup vs baseline: 1.6206x; 1.6206x over previous
//
#include <hip/hip_runtime.h>

// ConvGRU: 2-layer GRU, B=32, T=512, D=H=512, fp32 in/out, bf16 MFMA compute.
// Persistent wavefront pipeline, superstep s = layer0@t=s + layer1@t=s-1.
// Round-5: DATA via normal cached loads/stores (coalesced, L2/L3-served).
// Coherence via one __threadfence() per block per phase side (producer: wbL2
// before flag; consumer: inv after flag). Only the 64 barrier slots use
// relaxed agent-scope atomics. Weights register-resident (as round 4).

#define Bn 32
#define Tn 512
#define Dn 512
#define Hn 512
#define KKn 1024
#define NBLK 64
#define NTHR 192
#define NTHREADS (NBLK * NTHR)

typedef __bf16 bf16x8 __attribute__((ext_vector_type(8)));
typedef float floatx4 __attribute__((ext_vector_type(4)));

// ---- persistent device state ----
__device__ unsigned short g_h0b[2][Bn * Hn];   // layer0 h bf16 shadow (ping-pong)
__device__ unsigned short g_h1b[2][Bn * Hn];   // layer1 h bf16 shadow
__device__ unsigned short g_hr[2][Bn * Hn];    // h*r product bf16, per layer
__device__ float          g_u[2][Bn * Hn];     // u gate fp32, per layer
__device__ unsigned short g_xb[Bn * Tn * Dn];  // bf16 x
__device__ unsigned short g_Wrb[2 * Hn * KKn];
__device__ unsigned short g_Wub[2 * Hn * KKn];
__device__ unsigned short g_Wob[2 * Hn * KKn];
__device__ unsigned long long g_slot[NBLK * 8]; // per-block epoch slots

__device__ __forceinline__ bf16x8 ldb8(const unsigned short* p) {
    return *reinterpret_cast<const bf16x8*>(p);
}
__device__ __forceinline__ unsigned short f2b(float f) {
    union { float f; unsigned u; } v; v.f = f;
    unsigned u = v.u;
    return (unsigned short)((u + 0x7fffu + ((u >> 16) & 1u)) >> 16);  // RNE
}
__device__ __forceinline__ float b2fs(unsigned short b) {
    union { unsigned u; float f; } v; v.u = ((unsigned)b) << 16; return v.f;
}

// slot atomics only (relaxed agent scope)
__device__ __forceinline__ unsigned long long ald8(const void* p) {
    return __hip_atomic_load((const unsigned long long*)p, __ATOMIC_RELAXED,
                             __HIP_MEMORY_SCOPE_AGENT);
}
__device__ __forceinline__ void ast8(void* p, unsigned long long v) {
    __hip_atomic_store((unsigned long long*)p, v, __ATOMIC_RELAXED,
                       __HIP_MEMORY_SCOPE_AGENT);
}

// relaxed spin: 64 lanes scan the 64 block slots (no cache maintenance)
__device__ __forceinline__ void spin(unsigned long long tgt, int lane) {
    while (true) {
        unsigned long long v = ald8(&g_slot[lane * 8]);
        if (__all(v >= tgt)) break;
        __builtin_amdgcn_s_sleep(1);
    }
}

__device__ __forceinline__ void cvt_arr(const float* __restrict__ src,
                                        unsigned short* __restrict__ dst,
                                        int n, int gtid) {
    for (int i = gtid * 4; i < n; i += NTHREADS * 4) {
        floatx4 v = *reinterpret_cast<const floatx4*>(src + i);
        ushort4 pack = make_ushort4(f2b(v[0]), f2b(v[1]), f2b(v[2]), f2b(v[3]));
        *reinterpret_cast<ushort4*>(dst + i) = pack;
    }
}

__device__ __forceinline__ floatx4 mfma(bf16x8 a, bf16x8 b, floatx4 c) {
    return __builtin_amdgcn_mfma_f32_16x16x32_bf16(a, b, c, 0, 0, 0);
}

__global__ __launch_bounds__(NTHR, 1) void gru_persist(
    const float* __restrict__ x,
    const float* __restrict__ Wr, const float* __restrict__ br,
    const float* __restrict__ Wu, const float* __restrict__ bu,
    const float* __restrict__ Wo, const float* __restrict__ bo,
    float* __restrict__ out)
{
    const int tid  = threadIdx.x;
    const int lane = tid & 63;
    const int widx = tid >> 6;
    const int quad = lane >> 4;
    const int lo   = lane & 15;
    const bool isA = (widx < 2);
    const int gwA  = blockIdx.x * 2 + widx;  // 0..127 (A-waves)
    const int gwB  = blockIdx.x;             // 0..63  (B-waves)

    unsigned long long ep = ald8(&g_slot[blockIdx.x * 8]);

    // ---- launch init: zero h shadows; fp32 -> bf16 conversions (plain) ----
    {
        int gtid = blockIdx.x * NTHR + tid;
        unsigned* h0 = (unsigned*)&g_h0b[0][0];
        unsigned* h1 = (unsigned*)&g_h1b[0][0];
        for (int i = gtid; i < Bn * Hn; i += NTHREADS) {
            h0[i] = 0u;
            h1[i] = 0u;
        }
        cvt_arr(x,  g_xb,  Bn * Tn * Dn, gtid);
        cvt_arr(Wr, g_Wrb, 2 * Hn * KKn, gtid);
        cvt_arr(Wu, g_Wub, 2 * Hn * KKn, gtid);
        cvt_arr(Wo, g_Wob, 2 * Hn * KKn, gtid);
    }
    ep++;
    __syncthreads();                       // all waves' stores drained to L2
    if (tid == 0) { __threadfence(); ast8(&g_slot[blockIdx.x * 8], ep); }
    spin(ep, lane);
    if (widx == 0) __threadfence();        // inv L1+L2: see other blocks' data
    __syncthreads();

    // ---- role parameters + register-resident weights ----
    int lA = 0, gA = 0, n0A = 0, lB = 0, n0B = 0;
    float biasA = 0.f, biasB = 0.f;
    bf16x8 wreg[32];
    {
        const unsigned short* Wsrc;
        int nrow;
        if (isA) {
            lA = gwA >> 6; gA = (gwA >> 5) & 1; n0A = (gwA & 31) * 16;
            Wsrc = (gA ? g_Wrb : g_Wub) + (size_t)lA * Hn * KKn;
            nrow = n0A;
            biasA = (gA ? br : bu)[lA * Hn + n0A + lo];
        } else {
            lB = gwB >> 5; n0B = (gwB & 31) * 16;
            Wsrc = g_Wob + (size_t)lB * Hn * KKn;
            nrow = n0B;
            biasB = bo[lB * Hn + n0B + lo];
        }
        const unsigned short* wp = Wsrc + (size_t)(nrow + lo) * KKn + quad * 8;
        #pragma unroll
        for (int i = 0; i < 32; ++i) wreg[i] = ldb8(wp + i * 32);
    }

    // A layer0: precompute x-part for s=0
    floatx4 pacc0 = {0.f,0.f,0.f,0.f}, pacc1 = {0.f,0.f,0.f,0.f};
    if (isA && lA == 0) {
        const unsigned short* p0 = g_xb + (size_t)lo * (Tn * Dn) + quad * 8;
        const unsigned short* p1 = g_xb + (size_t)(16 + lo) * (Tn * Dn) + quad * 8;
        #pragma unroll
        for (int i = 0; i < 16; ++i) {
            pacc0 = mfma(ldb8(p0 + i * 32), wreg[i], pacc0);
            pacc1 = mfma(ldb8(p1 + i * 32), wreg[i], pacc1);
        }
    }
    float hreg0[4] = {0.f,0.f,0.f,0.f}, hreg1[4] = {0.f,0.f,0.f,0.f};
    floatx4 bacc0 = {0.f,0.f,0.f,0.f}, bacc1 = {0.f,0.f,0.f,0.f};

    for (int s = 0; s <= Tn; ++s) {
        const int cur = s & 1, nxt = cur ^ 1;

        // ===== Phase A compute (A-waves): u and h*r(sigmoid) =====
        if (isA) {
            bool actA = (lA == 0) ? (s < Tn) : (s >= 1);
            if (actA) {
                floatx4 a0, a1;
                const unsigned short* hs = (lA == 0) ? g_h0b[cur] : g_h1b[cur];
                if (lA == 0) { a0 = pacc0; a1 = pacc1; }
                else {
                    a0 = floatx4{0.f,0.f,0.f,0.f}; a1 = a0;
                    const unsigned short* p0 = g_h0b[cur] + (size_t)lo * Hn + quad * 8;
                    const unsigned short* p1 = g_h0b[cur] + (size_t)(16 + lo) * Hn + quad * 8;
                    #pragma unroll
                    for (int i = 0; i < 16; ++i) {
                        a0 = mfma(ldb8(p0 + i * 32), wreg[i], a0);
                        a1 = mfma(ldb8(p1 + i * 32), wreg[i], a1);
                    }
                }
                // r-waves: fetch own h-tile values (plain 2B loads)
                float hh0[4] = {0,0,0,0}, hh1[4] = {0,0,0,0};
                if (gA == 1) {
                    #pragma unroll
                    for (int rr = 0; rr < 4; ++rr) {
                        int b0 = quad * 4 + rr;
                        hh0[rr] = b2fs(hs[(size_t)b0 * Hn + n0A + lo]);
                        hh1[rr] = b2fs(hs[(size_t)(16 + b0) * Hn + n0A + lo]);
                    }
                }
                // h-part
                {
                    const unsigned short* p0 = hs + (size_t)lo * Hn + quad * 8;
                    const unsigned short* p1 = hs + (size_t)(16 + lo) * Hn + quad * 8;
                    #pragma unroll
                    for (int i = 0; i < 16; ++i) {
                        a0 = mfma(ldb8(p0 + i * 32), wreg[16 + i], a0);
                        a1 = mfma(ldb8(p1 + i * 32), wreg[16 + i], a1);
                    }
                }
                if (gA == 0) {
                    float* up = g_u[lA];
                    #pragma unroll
                    for (int rr = 0; rr < 4; ++rr) {
                        int b0 = quad * 4 + rr;
                        up[(size_t)b0 * Hn + n0A + lo] =
                            1.f / (1.f + __expf(-(a0[rr] + biasA)));
                        up[(size_t)(16 + b0) * Hn + n0A + lo] =
                            1.f / (1.f + __expf(-(a1[rr] + biasA)));
                    }
                } else {
                    unsigned short* hrp = g_hr[lA];
                    #pragma unroll
                    for (int rr = 0; rr < 4; ++rr) {
                        int b0 = quad * 4 + rr;
                        float r0 = 1.f / (1.f + __expf(-(a0[rr] + biasA)));
                        float r1 = 1.f / (1.f + __expf(-(a1[rr] + biasA)));
                        hrp[(size_t)b0 * Hn + n0A + lo] = f2b(hh0[rr] * r0);
                        hrp[(size_t)(16 + b0) * Hn + n0A + lo] = f2b(hh1[rr] * r1);
                    }
                }
            }
        }

        // ===== alpha barrier: arrive (producer fence + flag by tid0) =====
        ep++;
        __syncthreads();
        if (tid == 0) { __threadfence(); ast8(&g_slot[blockIdx.x * 8], ep); }

        // ===== precompute window (overlaps alpha spin) =====
        if (!isA) {
            bool act = (lB == 0) ? (s < Tn) : (s >= 1);
            bacc0 = floatx4{0.f,0.f,0.f,0.f}; bacc1 = bacc0;
            if (act) {
                if (lB == 0) {
                    const unsigned short* p0 = g_xb + (size_t)s * Dn + (size_t)lo * (Tn * Dn) + quad * 8;
                    const unsigned short* p1 = g_xb + (size_t)s * Dn + (size_t)(16 + lo) * (Tn * Dn) + quad * 8;
                    #pragma unroll
                    for (int i = 0; i < 16; ++i) {
                        bacc0 = mfma(ldb8(p0 + i * 32), wreg[i], bacc0);
                        bacc1 = mfma(ldb8(p1 + i * 32), wreg[i], bacc1);
                    }
                } else {
                    const unsigned short* p0 = g_h0b[cur] + (size_t)lo * Hn + quad * 8;
                    const unsigned short* p1 = g_h0b[cur] + (size_t)(16 + lo) * Hn + quad * 8;
                    #pragma unroll
                    for (int i = 0; i < 16; ++i) {
                        bacc0 = mfma(ldb8(p0 + i * 32), wreg[i], bacc0);
                        bacc1 = mfma(ldb8(p1 + i * 32), wreg[i], bacc1);
                    }
                }
            }
        } else if (lA == 0 && s + 1 < Tn) {
            const unsigned short* p0 = g_xb + (size_t)(s + 1) * Dn + (size_t)lo * (Tn * Dn) + quad * 8;
            const unsigned short* p1 = g_xb + (size_t)(s + 1) * Dn + (size_t)(16 + lo) * (Tn * Dn) + quad * 8;
            pacc0 = floatx4{0.f,0.f,0.f,0.f}; pacc1 = pacc0;
            #pragma unroll
            for (int i = 0; i < 16; ++i) {
                pacc0 = mfma(ldb8(p0 + i * 32), wreg[i], pacc0);
                pacc1 = mfma(ldb8(p1 + i * 32), wreg[i], pacc1);
            }
        }

        // ===== B-wave: spin alpha, consumer fence, then (h*r)@Wo + update =====
        if (!isA) {
            spin(ep, lane);
            __threadfence();   // inv: see A-waves' hr/u from all blocks
            bool act = (lB == 0) ? (s < Tn) : (s >= 1);
            if (act) {
                const unsigned short* HR = g_hr[lB];
                const unsigned short* p0 = HR + (size_t)lo * Hn + quad * 8;
                const unsigned short* p1 = HR + (size_t)(16 + lo) * Hn + quad * 8;
                #pragma unroll
                for (int i = 0; i < 16; ++i) {
                    bacc0 = mfma(ldb8(p0 + i * 32), wreg[16 + i], bacc0);
                    bacc1 = mfma(ldb8(p1 + i * 32), wreg[16 + i], bacc1);
                }
                const float* up = g_u[lB];
                unsigned short* hbn = (lB == 0) ? g_h0b[nxt] : g_h1b[nxt];
                bool fin = (lB == 0) ? (s == Tn - 1) : (s == Tn);
                #pragma unroll
                for (int rr = 0; rr < 4; ++rr) {
                    int b0 = quad * 4 + rr;
                    size_t i0 = (size_t)b0 * Hn + n0B + lo;
                    size_t i1 = (size_t)(16 + b0) * Hn + n0B + lo;
                    float o0 = tanhf(bacc0[rr] + biasB);
                    float o1 = tanhf(bacc1[rr] + biasB);
                    float u0 = up[i0];
                    float u1 = up[i1];
                    hreg0[rr] += u0 * (o0 - hreg0[rr]);
                    hreg1[rr] += u1 * (o1 - hreg1[rr]);
                    hbn[i0] = f2b(hreg0[rr]);
                    hbn[i1] = f2b(hreg1[rr]);
                    if (fin) {
                        out[(size_t)lB * Bn * Hn + i0] = hreg0[rr];
                        out[(size_t)lB * Bn * Hn + i1] = hreg1[rr];
                    }
                }
            }
        }

        // ===== beta barrier =====
        ep++;
        __syncthreads();
        if (tid == 0) { __threadfence(); ast8(&g_slot[blockIdx.x * 8], ep); }
        spin(ep, lane);
        if (widx == 0) __threadfence();   // inv once per CU; covers all waves
        __syncthreads();
    }
}

extern "C" void kernel_launch(void* const* d_in, const int* in_sizes, int n_in,
                              void* d_out, int out_size, void* d_ws, size_t ws_size,
                              hipStream_t stream) {
    const float* x  = (const float*)d_in[0];
    const float* Wr = (const float*)d_in[1];
    const float* br = (const float*)d_in[2];
    const float* Wu = (const float*)d_in[3];
    const float* bu = (const float*)d_in[4];
    const float* Wo = (const float*)d_in[5];
    const float* bo = (const float*)d_in[6];
    float* out = (float*)d_out;

    gru_persist<<<NBLK, NTHR, 0, stream>>>(x, Wr, br, Wu, bu, Wo, bo, out);
}

// Round 6
// 8870.750 us; speedup vs baseline: 1.7297x; 1.0673x over previous
//
#include <hip/hip_runtime.h>

// ConvGRU: 2-layer GRU, B=32, T=512, D=H=512, fp32 in/out, bf16 MFMA compute.
// Round-6: fence-free steady loop via write-once ring buffers.
//  - Producers publish state with relaxed agent-scope atomic stores (bypass L2
//    -> L3 directly; no wbl2). Consumers use normal cached loads; ring lines
//    are cold in every L2 (one inv at init), so fetches are guaranteed fresh,
//    and each XCD's L2 dedups the 8-block broadcast.
//  - Block b owns (layer, n-tile) for all 3 gates: wave0=u, wave1=r, wave2=o.
//    u passes via LDS (never global). hr/h go through rings.
//  - x-projections (layer0: x@Wu_x^T etc.) precomputed once per launch.

#define Bn 32
#define Tn 512
#define Dn 512
#define Hn 512
#define KKn 1024
#define NBLK 64
#define NTHR 192
#define NTHREADS (NBLK * NTHR)
#define RING (Tn + 2)

typedef __bf16 bf16x8 __attribute__((ext_vector_type(8)));
typedef float floatx4 __attribute__((ext_vector_type(4)));

// ---- persistent device state ----
__device__ unsigned short g_h0R[RING][Bn * Hn];   // h0 after t-1 at slot t
__device__ unsigned short g_h1R[RING][Bn * Hn];   // h1 after t'-1 at slot t'
__device__ unsigned short g_hr0R[RING][Bn * Hn];  // h0 (.) r0, slot s
__device__ unsigned short g_hr1R[RING][Bn * Hn];  // h1 (.) r1, slot s
__device__ unsigned short g_Xproj[3][Tn][Bn][Hn]; // bf16 x-projections (u,r,o)
__device__ unsigned short g_Wxb[3][Dn * Hn];      // layer0 x-half weights bf16
__device__ unsigned long long g_slot[NBLK * 8];   // per-block epoch slots

__device__ __forceinline__ bf16x8 ldb8(const unsigned short* p) {
    return *reinterpret_cast<const bf16x8*>(p);
}
__device__ __forceinline__ unsigned short f2b(float f) {
    union { float f; unsigned u; } v; v.f = f;
    unsigned u = v.u;
    return (unsigned short)((u + 0x7fffu + ((u >> 16) & 1u)) >> 16);  // RNE
}
__device__ __forceinline__ float b2fs(unsigned short b) {
    union { unsigned u; float f; } v; v.u = ((unsigned)b) << 16; return v.f;
}
__device__ __forceinline__ unsigned long long ald8(const void* p) {
    return __hip_atomic_load((const unsigned long long*)p, __ATOMIC_RELAXED,
                             __HIP_MEMORY_SCOPE_AGENT);
}
__device__ __forceinline__ void ast8(void* p, unsigned long long v) {
    __hip_atomic_store((unsigned long long*)p, v, __ATOMIC_RELAXED,
                       __HIP_MEMORY_SCOPE_AGENT);
}
__device__ __forceinline__ void ast4u(unsigned* p, unsigned v) {
    __hip_atomic_store(p, v, __ATOMIC_RELAXED, __HIP_MEMORY_SCOPE_AGENT);
}

__device__ __forceinline__ void spin(unsigned long long tgt, int lane) {
    while (true) {
        unsigned long long v = ald8(&g_slot[lane * 8]);
        if (__all(v >= tgt)) break;
        __builtin_amdgcn_s_sleep(1);
    }
}

__device__ __forceinline__ floatx4 mfma(bf16x8 a, bf16x8 b, floatx4 c) {
    return __builtin_amdgcn_mfma_f32_16x16x32_bf16(a, b, c, 0, 0, 0);
}
__device__ __forceinline__ bf16x8 cvt8(floatx4 v0, floatx4 v1) {
    bf16x8 a;
    a[0] = (__bf16)v0[0]; a[1] = (__bf16)v0[1]; a[2] = (__bf16)v0[2]; a[3] = (__bf16)v0[3];
    a[4] = (__bf16)v1[0]; a[5] = (__bf16)v1[1]; a[6] = (__bf16)v1[2]; a[7] = (__bf16)v1[3];
    return a;
}

__global__ __launch_bounds__(NTHR, 1) void gru_persist(
    const float* __restrict__ x,
    const float* __restrict__ Wr, const float* __restrict__ br,
    const float* __restrict__ Wu, const float* __restrict__ bu,
    const float* __restrict__ Wo, const float* __restrict__ bo,
    float* __restrict__ out)
{
    const int tid  = threadIdx.x;
    const int lane = tid & 63;
    const int widx = tid >> 6;          // 0=u-wave, 1=r-wave, 2=o/update-wave
    const int quad = lane >> 4;
    const int lo   = lane & 15;
    const int blk  = blockIdx.x;
    const int l    = blk >> 5;          // layer 0..1
    const int n0   = (blk & 31) * 16;   // n-tile

    __shared__ float lds_u[Bn * 16];

    unsigned long long ep = ald8(&g_slot[blk * 8]);

    // ================= phase 0: zero ring slot 0; cvt layer0 x-weights =====
    {
        int gtid = blk * NTHR + tid;
        unsigned* h0z = (unsigned*)&g_h0R[0][0];
        unsigned* h1z = (unsigned*)&g_h1R[0][0];
        for (int i = gtid; i < (Bn * Hn) / 2; i += NTHREADS) {
            h0z[i] = 0u;
            h1z[i] = 0u;
        }
        for (int i = gtid * 4; i < 3 * Dn * Hn; i += NTHREADS * 4) {
            int g = i / (Dn * Hn);
            int rem = i - g * (Dn * Hn);
            int n = rem >> 9, k = rem & 511;
            const float* ws = (g == 0) ? Wu : (g == 1) ? Wr : Wo;
            floatx4 v = *reinterpret_cast<const floatx4*>(ws + (size_t)n * KKn + k);
            ushort4 pk = make_ushort4(f2b(v[0]), f2b(v[1]), f2b(v[2]), f2b(v[3]));
            *reinterpret_cast<ushort4*>(&g_Wxb[0][0] + i) = pk;
        }
    }
    ep++;
    __syncthreads();
    if (tid == 0) { __threadfence(); ast8(&g_slot[blk * 8], ep); }
    spin(ep, lane);
    if (widx == 0) __threadfence();
    __syncthreads();

    // ================= phase 1: Xproj GEMM (layer0 x-projections) ==========
    {
        int gid = blk * 3 + widx;       // 0..191
        int g = gid >> 6;               // gate 0..2
        int chunk = gid & 63;           // 256 token-rows each
        for (int mt = 0; mt < 16; ++mt) {
            int m0 = chunk * 256 + mt * 16;
            int t = m0 >> 5;
            int bh = m0 & 31;           // 0 or 16
            const float* xrow = x + (size_t)(bh + lo) * Tn * Dn + (size_t)t * Dn + quad * 8;
            bf16x8 af[16];
            #pragma unroll
            for (int i = 0; i < 16; ++i) {
                floatx4 v0 = *reinterpret_cast<const floatx4*>(xrow + i * 32);
                floatx4 v1 = *reinterpret_cast<const floatx4*>(xrow + i * 32 + 4);
                af[i] = cvt8(v0, v1);
            }
            for (int nt = 0; nt < 32; ++nt) {
                floatx4 acc = {0.f, 0.f, 0.f, 0.f};
                const unsigned short* wp = &g_Wxb[g][0] + (size_t)(nt * 16 + lo) * Dn + quad * 8;
                #pragma unroll
                for (int i = 0; i < 16; ++i)
                    acc = mfma(af[i], ldb8(wp + i * 32), acc);
                #pragma unroll
                for (int rr = 0; rr < 4; ++rr)
                    g_Xproj[g][t][bh + quad * 4 + rr][nt * 16 + lo] = f2b(acc[rr]);
            }
        }
    }
    ep++;
    __syncthreads();
    if (tid == 0) { __threadfence(); ast8(&g_slot[blk * 8], ep); }
    spin(ep, lane);
    if (widx == 0) __threadfence();
    __syncthreads();

    // ================= register-resident recurrent weights =================
    // l==0: 16 frags (h-half, K=512). l==1: 32 frags (full K=1024).
    const int nfrag = (l == 0) ? 16 : 32;
    const float* Wsrc = (widx == 0) ? Wu : (widx == 1) ? Wr : Wo;
    const float bias = ((widx == 0) ? bu : (widx == 1) ? br : bo)[l * Hn + n0 + lo];
    bf16x8 wreg[32];
    {
        const int koff = (l == 0) ? Dn : 0;
        const float* wp = Wsrc + (size_t)l * Hn * KKn + (size_t)(n0 + lo) * KKn + koff + quad * 8;
        for (int i = 0; i < nfrag; ++i) {
            floatx4 v0 = *reinterpret_cast<const floatx4*>(wp + i * 32);
            floatx4 v1 = *reinterpret_cast<const floatx4*>(wp + i * 32 + 4);
            wreg[i] = cvt8(v0, v1);
        }
    }

    float hreg0[4] = {0.f, 0.f, 0.f, 0.f};
    float hreg1[4] = {0.f, 0.f, 0.f, 0.f};

    // ================= steady wavefront loop =================
    for (int s = 0; s <= Tn; ++s) {
        const bool act = (l == 0) ? (s < Tn) : (s >= 1);

        // ---- A-phase: u-wave and r-wave ----
        if (widx < 2 && act) {
            floatx4 a0 = {0.f, 0.f, 0.f, 0.f}, a1 = a0;
            if (l == 0) {
                const unsigned short* xp = &g_Xproj[widx][s][0][n0 + lo];
                #pragma unroll
                for (int rr = 0; rr < 4; ++rr) {
                    a0[rr] = b2fs(xp[(size_t)(quad * 4 + rr) * Hn]);
                    a1[rr] = b2fs(xp[(size_t)(16 + quad * 4 + rr) * Hn]);
                }
                const unsigned short* h = g_h0R[s];
                const unsigned short* p0 = h + (size_t)lo * Hn + quad * 8;
                const unsigned short* p1 = h + (size_t)(16 + lo) * Hn + quad * 8;
                #pragma unroll
                for (int i = 0; i < 16; ++i) {
                    a0 = mfma(ldb8(p0 + i * 32), wreg[i], a0);
                    a1 = mfma(ldb8(p1 + i * 32), wreg[i], a1);
                }
            } else {
                const unsigned short* h0 = g_h0R[s];
                const unsigned short* h1 = g_h1R[s - 1];
                const unsigned short* p0 = h0 + (size_t)lo * Hn + quad * 8;
                const unsigned short* p1 = h0 + (size_t)(16 + lo) * Hn + quad * 8;
                const unsigned short* q0 = h1 + (size_t)lo * Hn + quad * 8;
                const unsigned short* q1 = h1 + (size_t)(16 + lo) * Hn + quad * 8;
                #pragma unroll
                for (int i = 0; i < 16; ++i) {
                    a0 = mfma(ldb8(p0 + i * 32), wreg[i], a0);
                    a1 = mfma(ldb8(p1 + i * 32), wreg[i], a1);
                }
                #pragma unroll
                for (int i = 0; i < 16; ++i) {
                    a0 = mfma(ldb8(q0 + i * 32), wreg[16 + i], a0);
                    a1 = mfma(ldb8(q1 + i * 32), wreg[16 + i], a1);
                }
            }
            if (widx == 0) {
                // u -> LDS (block-local)
                #pragma unroll
                for (int rr = 0; rr < 4; ++rr) {
                    int r0 = quad * 4 + rr;
                    lds_u[r0 * 16 + lo] = 1.f / (1.f + __expf(-(a0[rr] + bias)));
                    lds_u[(16 + r0) * 16 + lo] = 1.f / (1.f + __expf(-(a1[rr] + bias)));
                }
            } else {
                // r -> hr = h (.) r -> bypass store to ring
                const unsigned short* h = (l == 0) ? g_h0R[s] : g_h1R[s - 1];
                unsigned short* hr = (l == 0) ? g_hr0R[s] : g_hr1R[s];
                #pragma unroll
                for (int rr = 0; rr < 4; ++rr) {
                    int r0 = quad * 4 + rr;
                    float rv0 = 1.f / (1.f + __expf(-(a0[rr] + bias)));
                    float rv1 = 1.f / (1.f + __expf(-(a1[rr] + bias)));
                    float hv0 = b2fs(h[(size_t)r0 * Hn + n0 + lo]);
                    float hv1 = b2fs(h[(size_t)(16 + r0) * Hn + n0 + lo]);
                    unsigned w0 = f2b(hv0 * rv0), w1 = f2b(hv1 * rv1);
                    unsigned pp0 = (unsigned)__shfl_xor((int)w0, 1);
                    unsigned pp1 = (unsigned)__shfl_xor((int)w1, 1);
                    if ((lo & 1) == 0) {
                        ast4u((unsigned*)(hr + (size_t)r0 * Hn + n0 + lo), w0 | (pp0 << 16));
                        ast4u((unsigned*)(hr + (size_t)(16 + r0) * Hn + n0 + lo), w1 | (pp1 << 16));
                    }
                }
            }
        }

        // ---- alpha barrier: arrive ----
        ep++;
        __syncthreads();
        if (tid == 0) ast8(&g_slot[blk * 8], ep);

        // ---- B-wave: precompute x-part, spin, (h.r)@Wo + update ----
        if (widx == 2) {
            floatx4 a0 = {0.f, 0.f, 0.f, 0.f}, a1 = a0;
            if (act) {
                if (l == 0) {
                    const unsigned short* xp = &g_Xproj[2][s][0][n0 + lo];
                    #pragma unroll
                    for (int rr = 0; rr < 4; ++rr) {
                        a0[rr] = b2fs(xp[(size_t)(quad * 4 + rr) * Hn]);
                        a1[rr] = b2fs(xp[(size_t)(16 + quad * 4 + rr) * Hn]);
                    }
                } else {
                    const unsigned short* h0 = g_h0R[s];
                    const unsigned short* p0 = h0 + (size_t)lo * Hn + quad * 8;
                    const unsigned short* p1 = h0 + (size_t)(16 + lo) * Hn + quad * 8;
                    #pragma unroll
                    for (int i = 0; i < 16; ++i) {
                        a0 = mfma(ldb8(p0 + i * 32), wreg[i], a0);
                        a1 = mfma(ldb8(p1 + i * 32), wreg[i], a1);
                    }
                }
            }
            spin(ep, lane);
            if (act) {
                const unsigned short* hr = (l == 0) ? g_hr0R[s] : g_hr1R[s];
                const unsigned short* p0 = hr + (size_t)lo * Hn + quad * 8;
                const unsigned short* p1 = hr + (size_t)(16 + lo) * Hn + quad * 8;
                const int wb = (l == 0) ? 0 : 16;
                #pragma unroll
                for (int i = 0; i < 16; ++i) {
                    a0 = mfma(ldb8(p0 + i * 32), wreg[wb + i], a0);
                    a1 = mfma(ldb8(p1 + i * 32), wreg[wb + i], a1);
                }
                unsigned short* hpub = (l == 0) ? g_h0R[s + 1] : g_h1R[s];
                bool fin = (l == 0) ? (s == Tn - 1) : (s == Tn);
                #pragma unroll
                for (int rr = 0; rr < 4; ++rr) {
                    int r0 = quad * 4 + rr;
                    float o0 = tanhf(a0[rr] + bias);
                    float o1 = tanhf(a1[rr] + bias);
                    float u0 = lds_u[r0 * 16 + lo];
                    float u1 = lds_u[(16 + r0) * 16 + lo];
                    hreg0[rr] += u0 * (o0 - hreg0[rr]);
                    hreg1[rr] += u1 * (o1 - hreg1[rr]);
                    unsigned w0 = f2b(hreg0[rr]), w1 = f2b(hreg1[rr]);
                    unsigned pp0 = (unsigned)__shfl_xor((int)w0, 1);
                    unsigned pp1 = (unsigned)__shfl_xor((int)w1, 1);
                    if ((lo & 1) == 0) {
                        ast4u((unsigned*)(hpub + (size_t)r0 * Hn + n0 + lo), w0 | (pp0 << 16));
                        ast4u((unsigned*)(hpub + (size_t)(16 + r0) * Hn + n0 + lo), w1 | (pp1 << 16));
                    }
                    if (fin) {
                        out[(size_t)l * Bn * Hn + (size_t)r0 * Hn + n0 + lo] = hreg0[rr];
                        out[(size_t)l * Bn * Hn + (size_t)(16 + r0) * Hn + n0 + lo] = hreg1[rr];
                    }
                }
            }
        }

        // ---- beta barrier ----
        ep++;
        __syncthreads();
        if (tid == 0) ast8(&g_slot[blk * 8], ep);
        spin(ep, lane);
    }
}

extern "C" void kernel_launch(void* const* d_in, const int* in_sizes, int n_in,
                              void* d_out, int out_size, void* d_ws, size_t ws_size,
                              hipStream_t stream) {
    const float* x  = (const float*)d_in[0];
    const float* Wr = (const float*)d_in[1];
    const float* br = (const float*)d_in[2];
    const float* Wu = (const float*)d_in[3];
    const float* bu = (const float*)d_in[4];
    const float* Wo = (const float*)d_in[5];
    const float* bo = (const float*)d_in[6];
    float* out = (float*)d_out;

    gru_persist<<<NBLK, NTHR, 0, stream>>>(x, Wr, br, Wu, bu, Wo, bo, out);
}